// Round 1
// baseline (614.838 us; speedup 1.0000x reference)
//
#include <hip/hip_runtime.h>
#include <hip/hip_bf16.h>

#define NN 4096      // nodes
#define ED 1024      // edim
#define WF 1024      // wfeat
#define SLOPEC 0.01f
#define NEG_INFC -1e9f

typedef __attribute__((ext_vector_type(8))) short bf16x8;
typedef __attribute__((ext_vector_type(4))) short short4v;
typedef __attribute__((ext_vector_type(4))) float f32x4;

__device__ __forceinline__ float bf2f(short s) {
    union { unsigned u; float f; } v;
    v.u = ((unsigned)(unsigned short)s) << 16;
    return v.f;
}
__device__ __forceinline__ short f2bf(float f) {
    unsigned u = __float_as_uint(f);
    unsigned r = u + 0x7FFFu + ((u >> 16) & 1u);   // RNE (finite data)
    return (short)(r >> 16);
}

// ---------------------------------------------------------------------------
// Transpose + convert W [ED][WF] fp32 -> Wt [WF][ED] bf16
// ---------------------------------------------------------------------------
__global__ __launch_bounds__(256) void k_wt(const float* __restrict__ W,
                                            short* __restrict__ Wt) {
    __shared__ float t[64][65];
    const int k0 = blockIdx.y * 64, n0 = blockIdx.x * 64;
    const int tx = threadIdx.x & 63, ty = threadIdx.x >> 6;
#pragma unroll
    for (int p = 0; p < 16; p++) {
        int r = p * 4 + ty;
        t[r][tx] = W[(long)(k0 + r) * WF + n0 + tx];
    }
    __syncthreads();
#pragma unroll
    for (int p = 0; p < 16; p++) {
        int r = p * 4 + ty;  // n index
        Wt[(long)(n0 + r) * ED + k0 + tx] = f2bf(t[tx][r]);
    }
}

// ---------------------------------------------------------------------------
// GEMM: C[M][Nf] = A[M][K] (fp32, optional row gather) * Bt[Nf][K] (bf16)
// BM=128 BN=64 BK=32, 256 threads = 4 waves (2x2), 16x16x32 bf16 MFMA.
// EPI_HT: write D transposed as bf16 to Ht[Nf][M].
// else:   write D fp32 to C[M][ldc] and atomicAdd column sums into pool.
// ---------------------------------------------------------------------------
template <bool GATHER, bool EPI_HT>
__global__ __launch_bounds__(256, 2) void gemm_bt(
    const float* __restrict__ A, const int* __restrict__ rowidx,
    const short* __restrict__ Bt, int M, int Nf, int K, int lda,
    short* __restrict__ Ht, float* __restrict__ C, int ldc,
    float* __restrict__ pool) {
    __shared__ __align__(16) short sA[128 * 32];
    __shared__ __align__(16) short sB[64 * 32];
    __shared__ __align__(16) short sT[EPI_HT ? 64 * 128 : 8];
    __shared__ int sIdx[128];

    const int tid = threadIdx.x;
    const int lane = tid & 63;
    const int wid = tid >> 6;
    const int wm = wid >> 1, wn = wid & 1;
    const int m0 = blockIdx.y * 128;
    const int n0 = blockIdx.x * 64;

    if (GATHER) {
        if (tid < 128) sIdx[tid] = rowidx[m0 + tid];
        __syncthreads();
    }

    f32x4 acc[4][2];
#pragma unroll
    for (int t = 0; t < 4; t++)
#pragma unroll
        for (int u = 0; u < 2; u++) acc[t][u] = (f32x4){0.f, 0.f, 0.f, 0.f};

    const int ar = tid >> 3;         // 0..31 (row within pass)
    const int ac = (tid & 7) * 4;    // 0..28
    const int br = tid >> 2;         // 0..63
    const int bc = (tid & 3) * 8;    // 0..24

    const int l15 = lane & 15;
    const int lhi = lane >> 4;

    for (int k0 = 0; k0 < K; k0 += 32) {
        // stage A tile 128x32 fp32 -> bf16
#pragma unroll
        for (int p = 0; p < 4; p++) {
            int row = p * 32 + ar;
            long rbase;
            if (GATHER) rbase = (long)sIdx[row] * lda;
            else        rbase = (long)(m0 + row) * lda;
            const float4 v = *(const float4*)(A + rbase + k0 + ac);
            short4v s;
            s.x = f2bf(v.x); s.y = f2bf(v.y); s.z = f2bf(v.z); s.w = f2bf(v.w);
            *(short4v*)&sA[row * 32 + ac] = s;
        }
        // stage B tile 64x32 bf16
        {
            const bf16x8 v = *(const bf16x8*)(Bt + (long)(n0 + br) * K + k0 + bc);
            *(bf16x8*)&sB[br * 32 + bc] = v;
        }
        __syncthreads();

        bf16x8 af[4], bfr[2];
#pragma unroll
        for (int t = 0; t < 4; t++)
            af[t] = *(const bf16x8*)&sA[(wm * 64 + t * 16 + l15) * 32 + lhi * 8];
#pragma unroll
        for (int u = 0; u < 2; u++)
            bfr[u] = *(const bf16x8*)&sB[(wn * 32 + u * 16 + l15) * 32 + lhi * 8];
#pragma unroll
        for (int t = 0; t < 4; t++)
#pragma unroll
            for (int u = 0; u < 2; u++)
                acc[t][u] = __builtin_amdgcn_mfma_f32_16x16x32_bf16(
                    af[t], bfr[u], acc[t][u], 0, 0, 0);
        __syncthreads();
    }

    if (EPI_HT) {
        // D[m][n] -> Ht[n0+n][m0+m] bf16 via LDS transpose
#pragma unroll
        for (int t = 0; t < 4; t++)
#pragma unroll
            for (int u = 0; u < 2; u++)
#pragma unroll
                for (int r = 0; r < 4; r++) {
                    int m = wm * 64 + t * 16 + lhi * 4 + r;
                    int n = wn * 32 + u * 16 + l15;
                    sT[n * 128 + m] = f2bf(acc[t][u][r]);
                }
        __syncthreads();
#pragma unroll
        for (int p = 0; p < 4; p++) {
            int row = p * 16 + (tid >> 4);
            int c = (tid & 15) * 8;
            *(bf16x8*)(Ht + (long)(n0 + row) * M + m0 + c) =
                *(const bf16x8*)&sT[row * 128 + c];
        }
    } else {
#pragma unroll
        for (int u = 0; u < 2; u++) {
            float colsum = 0.f;
#pragma unroll
            for (int t = 0; t < 4; t++)
#pragma unroll
                for (int r = 0; r < 4; r++) {
                    int m = wm * 64 + t * 16 + lhi * 4 + r;
                    int n = wn * 32 + u * 16 + l15;
                    C[(long)(m0 + m) * ldc + n0 + n] = acc[t][u][r];
                    colsum += acc[t][u][r];
                }
            colsum += __shfl_down(colsum, 32);
            colsum += __shfl_down(colsum, 16);
            if (lane < 16) atomicAdd(pool + n0 + wn * 32 + u * 16 + lane, colsum);
        }
    }
}

// ---------------------------------------------------------------------------
// s_src[i] = sum_f Ht[f][i]*a_src[f]; s_dst likewise
// ---------------------------------------------------------------------------
__global__ __launch_bounds__(256) void k_scores(const short* __restrict__ Ht,
                                                const float* __restrict__ a_src,
                                                const float* __restrict__ a_dst,
                                                float* __restrict__ s_src,
                                                float* __restrict__ s_dst) {
    const int i = blockIdx.x * 256 + threadIdx.x;
    float as = 0.f, ad = 0.f;
#pragma unroll 8
    for (int f = 0; f < WF; f++) {
        float hv = bf2f(Ht[(long)f * NN + i]);
        as += hv * a_src[f];
        ad += hv * a_dst[f];
    }
    s_src[i] = as;
    s_dst[i] = ad;
}

// ---------------------------------------------------------------------------
// Masked softmax row: attention[row][:] fp32 to d_out
// ---------------------------------------------------------------------------
__global__ __launch_bounds__(256) void k_attn(const int* __restrict__ adj,
                                              const float* __restrict__ s_src,
                                              const float* __restrict__ s_dst,
                                              float* __restrict__ attn) {
    __shared__ float wred[4];
    __shared__ float wred2[4];
    const int row = blockIdx.x;
    const int tid = threadIdx.x;
    const float ss = s_src[row];
    const int4* adj4 = (const int4*)(adj + (long)row * NN);
    const float4* sd4 = (const float4*)s_dst;
    float v[16];
    float vmax = -3e38f;
#pragma unroll
    for (int c = 0; c < 4; c++) {
        int idx = c * 256 + tid;
        int4 a = adj4[idx];
        float4 d = sd4[idx];
        float x0 = ss + d.x; x0 = x0 > 0.f ? x0 : SLOPEC * x0; x0 = a.x > 0 ? x0 : NEG_INFC;
        float x1 = ss + d.y; x1 = x1 > 0.f ? x1 : SLOPEC * x1; x1 = a.y > 0 ? x1 : NEG_INFC;
        float x2 = ss + d.z; x2 = x2 > 0.f ? x2 : SLOPEC * x2; x2 = a.z > 0 ? x2 : NEG_INFC;
        float x3 = ss + d.w; x3 = x3 > 0.f ? x3 : SLOPEC * x3; x3 = a.w > 0 ? x3 : NEG_INFC;
        v[c * 4 + 0] = x0; v[c * 4 + 1] = x1; v[c * 4 + 2] = x2; v[c * 4 + 3] = x3;
        vmax = fmaxf(vmax, fmaxf(fmaxf(x0, x1), fmaxf(x2, x3)));
    }
#pragma unroll
    for (int off = 32; off; off >>= 1) vmax = fmaxf(vmax, __shfl_xor(vmax, off));
    if ((tid & 63) == 0) wred[tid >> 6] = vmax;
    __syncthreads();
    vmax = fmaxf(fmaxf(wred[0], wred[1]), fmaxf(wred[2], wred[3]));

    float sum = 0.f;
#pragma unroll
    for (int c = 0; c < 16; c++) {
        v[c] = __expf(v[c] - vmax);
        sum += v[c];
    }
#pragma unroll
    for (int off = 32; off; off >>= 1) sum += __shfl_xor(sum, off);
    if ((tid & 63) == 0) wred2[tid >> 6] = sum;
    __syncthreads();
    sum = wred2[0] + wred2[1] + wred2[2] + wred2[3];
    const float inv = 1.0f / sum;

    float4* o4 = (float4*)(attn + (long)row * NN);
#pragma unroll
    for (int c = 0; c < 4; c++) {
        int idx = c * 256 + tid;
        float4 o;
        o.x = v[c * 4 + 0] * inv; o.y = v[c * 4 + 1] * inv;
        o.z = v[c * 4 + 2] * inv; o.w = v[c * 4 + 3] * inv;
        o4[idx] = o;
    }
}

// ---------------------------------------------------------------------------
// pool mean + classifier + 2-way softmax
// ---------------------------------------------------------------------------
__global__ __launch_bounds__(256) void k_final(const float* __restrict__ pool_acc,
                                               const float* __restrict__ clf_w,
                                               const float* __restrict__ clf_b,
                                               float* __restrict__ out_pool,
                                               float* __restrict__ out_label) {
    __shared__ float r0[4], r1[4];
    const int tid = threadIdx.x;
    float l0 = 0.f, l1 = 0.f;
#pragma unroll
    for (int q = 0; q < 4; q++) {
        int f = q * 256 + tid;
        float p = pool_acc[f] * (1.0f / NN);
        out_pool[f] = p;
        l0 += p * clf_w[f * 2 + 0];
        l1 += p * clf_w[f * 2 + 1];
    }
#pragma unroll
    for (int off = 32; off; off >>= 1) {
        l0 += __shfl_xor(l0, off);
        l1 += __shfl_xor(l1, off);
    }
    if ((tid & 63) == 0) { r0[tid >> 6] = l0; r1[tid >> 6] = l1; }
    __syncthreads();
    if (tid == 0) {
        float L0 = r0[0] + r0[1] + r0[2] + r0[3] + clf_b[0];
        float L1 = r1[0] + r1[1] + r1[2] + r1[3] + clf_b[1];
        float m = fmaxf(L0, L1);
        float e0 = __expf(L0 - m), e1 = __expf(L1 - m);
        float s = e0 + e1;
        out_label[0] = e0 / s;
        out_label[1] = e1 / s;
    }
}

// ---------------------------------------------------------------------------
extern "C" void kernel_launch(void* const* d_in, const int* in_sizes, int n_in,
                              void* d_out, int out_size, void* d_ws,
                              size_t ws_size, hipStream_t stream) {
    const int* inSen = (const int*)d_in[0];
    const int* adj = (const int*)d_in[1];
    const float* emb = (const float*)d_in[2];
    const float* W = (const float*)d_in[3];
    const float* a_src = (const float*)d_in[4];
    const float* a_dst = (const float*)d_in[5];
    const float* clf_w = (const float*)d_in[6];
    const float* clf_b = (const float*)d_in[7];

    float* out = (float*)d_out;
    float* out_pool = out;
    float* attn = out + 1024;
    float* sentence = out + 1024 + (long)NN * NN;
    float* out_label = out + 1024 + (long)NN * NN + (long)NN * WF;

    char* ws = (char*)d_ws;
    short* Ht = (short*)ws;                                   // WF*NN bf16 = 8 MB
    float* s_src = (float*)(ws + 8388608);                    // 16 KB
    float* s_dst = (float*)(ws + 8388608 + 16384);            // 16 KB
    float* pool = (float*)(ws + 8388608 + 32768);             // 4 KB
    short* Wt = (short*)(ws + 8388608 + 32768 + 4096);        // 2 MB

    hipMemsetAsync(pool, 0, 1024 * sizeof(float), stream);

    k_wt<<<dim3(16, 16), 256, 0, stream>>>(W, Wt);

    // h^T = (emb[inSen] @ W)^T : M=NN K=ED Nf=WF
    gemm_bt<true, true><<<dim3(WF / 64, NN / 128), 256, 0, stream>>>(
        emb, inSen, Wt, NN, WF, ED, ED, Ht, nullptr, 0, nullptr);

    k_scores<<<NN / 256, 256, 0, stream>>>(Ht, a_src, a_dst, s_src, s_dst);

    k_attn<<<NN, 256, 0, stream>>>(adj, s_src, s_dst, attn);

    // sentence = attention @ h : M=NN K=NN Nf=WF (A fp32 from d_out)
    gemm_bt<false, false><<<dim3(WF / 64, NN / 128), 256, 0, stream>>>(
        attn, nullptr, Ht, NN, WF, NN, NN, nullptr, sentence, WF, pool);

    k_final<<<1, 256, 0, stream>>>(pool, clf_w, clf_b, out_pool, out_label);
}

// Round 2
// 470.490 us; speedup vs baseline: 1.3068x; 1.3068x over previous
//
#include <hip/hip_runtime.h>
#include <hip/hip_bf16.h>

#define NN 4096      // nodes
#define ED 1024      // edim
#define WF 1024      // wfeat
#define SLOPEC 0.01f
#define NEG_INFC -1e9f

typedef __attribute__((ext_vector_type(8))) short bf16x8;
typedef __attribute__((ext_vector_type(4))) short short4v;
typedef __attribute__((ext_vector_type(4))) float f32x4;

__device__ __forceinline__ float bf2f(short s) {
    union { unsigned u; float f; } v;
    v.u = ((unsigned)(unsigned short)s) << 16;
    return v.f;
}
__device__ __forceinline__ short f2bf(float f) {
    unsigned u = __float_as_uint(f);
    unsigned r = u + 0x7FFFu + ((u >> 16) & 1u);   // RNE (finite data)
    return (short)(r >> 16);
}

typedef __attribute__((address_space(3))) unsigned lds_u32;
typedef const __attribute__((address_space(1))) unsigned gbl_u32;
__device__ __forceinline__ void g2l16(const short* g, short* l) {
    __builtin_amdgcn_global_load_lds((gbl_u32*)g, (lds_u32*)l, 16, 0, 0);
}

// ---------------------------------------------------------------------------
// Transpose + convert W [ED][WF] fp32 -> Wt [WF][ED] bf16
// ---------------------------------------------------------------------------
__global__ __launch_bounds__(256) void k_wt(const float* __restrict__ W,
                                            short* __restrict__ Wt) {
    __shared__ float t[64][65];
    const int k0 = blockIdx.y * 64, n0 = blockIdx.x * 64;
    const int tx = threadIdx.x & 63, ty = threadIdx.x >> 6;
#pragma unroll
    for (int p = 0; p < 16; p++) {
        int r = p * 4 + ty;
        t[r][tx] = W[(long)(k0 + r) * WF + n0 + tx];
    }
    __syncthreads();
#pragma unroll
    for (int p = 0; p < 16; p++) {
        int r = p * 4 + ty;  // n index
        Wt[(long)(n0 + r) * ED + k0 + tx] = f2bf(t[tx][r]);
    }
}

// ---------------------------------------------------------------------------
// Gather + convert: X[i][k] = bf16(emb[inSen[i]][k]),  X: [NN][ED]
// ---------------------------------------------------------------------------
__global__ __launch_bounds__(256) void k_gather(const int* __restrict__ inSen,
                                                const float* __restrict__ emb,
                                                short* __restrict__ X) {
    const int row = blockIdx.x;
    const int tid = threadIdx.x;
    const long idx = inSen[row];
    const float4 v = ((const float4*)(emb + idx * ED))[tid];
    short4v s;
    s.x = f2bf(v.x); s.y = f2bf(v.y); s.z = f2bf(v.z); s.w = f2bf(v.w);
    *(short4v*)(X + (long)row * ED + tid * 4) = s;
}

// ---------------------------------------------------------------------------
// GEMM (m97 structure): C[M][N] += A[M][K] * Bt[N][K], all bf16 in, fp32 out.
// BM=BN=128, BK=32, 256 thr = 4 waves (2x2), each wave 64x64 = 4x4 MFMAs.
// Staging via global_load_lds width=16. Split-K over blockIdx.z (chunk Kc).
// ATOMIC_OUT: atomicAdd into Cout[M][N]  (zero-initialized by caller)
// else:       store fp32 partial at P + bz*M*N
// ---------------------------------------------------------------------------
template <bool ATOMIC_OUT>
__global__ __launch_bounds__(256, 2) void gemm_bt2(
    const short* __restrict__ A, const short* __restrict__ Bt,
    int M, int N, int K, int Kc, float* __restrict__ Cout) {
    __shared__ __align__(16) short sA[128 * 32];
    __shared__ __align__(16) short sB[128 * 32];

    const int tid = threadIdx.x;
    const int lane = tid & 63;
    const int wid = tid >> 6;
    const int wm = wid >> 1, wn = wid & 1;
    const int n0 = blockIdx.x * 128;
    const int m0 = blockIdx.y * 128;
    const int ks = blockIdx.z * Kc;

    const int srow = tid >> 2;        // 0..63
    const int sc8 = (tid & 3) * 8;    // 0,8,16,24
    const int l15 = lane & 15;
    const int lhi = lane >> 4;

    f32x4 acc[4][4];
#pragma unroll
    for (int t = 0; t < 4; t++)
#pragma unroll
        for (int u = 0; u < 4; u++) acc[t][u] = (f32x4){0.f, 0.f, 0.f, 0.f};

    const short* Ab = A + (long)(m0 + srow) * K + ks + sc8;
    const short* Bb = Bt + (long)(n0 + srow) * K + ks + sc8;
    // wave-uniform LDS bases (lane data lands at base + lane*16B)
    short* lA0 = sA + (long)(wid * 64) * 8;
    short* lA1 = sA + (long)(256 + wid * 64) * 8;
    short* lB0 = sB + (long)(wid * 64) * 8;
    short* lB1 = sB + (long)(256 + wid * 64) * 8;
    const long rstep = (long)64 * K;   // 64 rows

    for (int k0 = 0; k0 < Kc; k0 += 32) {
        g2l16(Ab + k0, lA0);
        g2l16(Ab + rstep + k0, lA1);
        g2l16(Bb + k0, lB0);
        g2l16(Bb + rstep + k0, lB1);
        __syncthreads();   // waits vmcnt(0) for global_load_lds

        bf16x8 af[4], bfr[4];
#pragma unroll
        for (int t = 0; t < 4; t++)
            af[t] = *(const bf16x8*)&sA[(wm * 64 + t * 16 + l15) * 32 + lhi * 8];
#pragma unroll
        for (int u = 0; u < 4; u++)
            bfr[u] = *(const bf16x8*)&sB[(wn * 64 + u * 16 + l15) * 32 + lhi * 8];
#pragma unroll
        for (int t = 0; t < 4; t++)
#pragma unroll
            for (int u = 0; u < 4; u++)
                acc[t][u] = __builtin_amdgcn_mfma_f32_16x16x32_bf16(
                    af[t], bfr[u], acc[t][u], 0, 0, 0);
        __syncthreads();
    }

    // Epilogue. D mapping per 16x16 tile: col = l15, row = lhi*4 + r
    if (ATOMIC_OUT) {
#pragma unroll
        for (int t = 0; t < 4; t++)
#pragma unroll
            for (int u = 0; u < 4; u++)
#pragma unroll
                for (int r = 0; r < 4; r++) {
                    int m = wm * 64 + t * 16 + lhi * 4 + r;
                    int n = wn * 64 + u * 16 + l15;
                    atomicAdd(Cout + (long)(m0 + m) * N + n0 + n, acc[t][u][r]);
                }
    } else {
        float* P = Cout + (long)blockIdx.z * M * N;
#pragma unroll
        for (int t = 0; t < 4; t++)
#pragma unroll
            for (int u = 0; u < 4; u++)
#pragma unroll
                for (int r = 0; r < 4; r++) {
                    int m = wm * 64 + t * 16 + lhi * 4 + r;
                    int n = wn * 64 + u * 16 + l15;
                    P[(long)(m0 + m) * N + n0 + n] = acc[t][u][r];
                }
    }
}

// ---------------------------------------------------------------------------
// reduce1: Ht[e] = bf16(P[0][e] + P[1][e]), e over M*N = 1024*4096
// ---------------------------------------------------------------------------
__global__ __launch_bounds__(256) void k_reduce1(const float* __restrict__ P,
                                                 short* __restrict__ Ht) {
    const long e = ((long)blockIdx.x * 256 + threadIdx.x) * 8;
    const long MN = (long)WF * NN;
    const float4 a0 = *(const float4*)(P + e);
    const float4 a1 = *(const float4*)(P + e + 4);
    const float4 b0 = *(const float4*)(P + MN + e);
    const float4 b1 = *(const float4*)(P + MN + e + 4);
    bf16x8 o;
    o[0] = f2bf(a0.x + b0.x); o[1] = f2bf(a0.y + b0.y);
    o[2] = f2bf(a0.z + b0.z); o[3] = f2bf(a0.w + b0.w);
    o[4] = f2bf(a1.x + b1.x); o[5] = f2bf(a1.y + b1.y);
    o[6] = f2bf(a1.z + b1.z); o[7] = f2bf(a1.w + b1.w);
    *(bf16x8*)(Ht + e) = o;
}

// ---------------------------------------------------------------------------
// scores: s_src[i] += sum_{f in chunk} Ht[f][i]*a_src[f]   (atomic over chunks)
// grid (NN/256, WF/256)
// ---------------------------------------------------------------------------
__global__ __launch_bounds__(256) void k_scores(const short* __restrict__ Ht,
                                                const float* __restrict__ a_src,
                                                const float* __restrict__ a_dst,
                                                float* __restrict__ s_src,
                                                float* __restrict__ s_dst) {
    const int i = blockIdx.x * 256 + threadIdx.x;
    const int f0 = blockIdx.y * 256;
    float as = 0.f, ad = 0.f;
#pragma unroll 8
    for (int f = f0; f < f0 + 256; f++) {
        float hv = bf2f(Ht[(long)f * NN + i]);
        as += hv * a_src[f];
        ad += hv * a_dst[f];
    }
    atomicAdd(s_src + i, as);
    atomicAdd(s_dst + i, ad);
}

// ---------------------------------------------------------------------------
// Masked softmax row -> attn fp32 (d_out) + attnB bf16 (ws, GEMM2 A operand)
// ---------------------------------------------------------------------------
__global__ __launch_bounds__(256) void k_attn(const int* __restrict__ adj,
                                              const float* __restrict__ s_src,
                                              const float* __restrict__ s_dst,
                                              float* __restrict__ attn,
                                              short* __restrict__ attnB) {
    __shared__ float wred[4];
    __shared__ float wred2[4];
    const int row = blockIdx.x;
    const int tid = threadIdx.x;
    const float ss = s_src[row];
    const int4* adj4 = (const int4*)(adj + (long)row * NN);
    const float4* sd4 = (const float4*)s_dst;
    float v[16];
    float vmax = -3e38f;
#pragma unroll
    for (int c = 0; c < 4; c++) {
        int idx = c * 256 + tid;
        int4 a = adj4[idx];
        float4 d = sd4[idx];
        float x0 = ss + d.x; x0 = x0 > 0.f ? x0 : SLOPEC * x0; x0 = a.x > 0 ? x0 : NEG_INFC;
        float x1 = ss + d.y; x1 = x1 > 0.f ? x1 : SLOPEC * x1; x1 = a.y > 0 ? x1 : NEG_INFC;
        float x2 = ss + d.z; x2 = x2 > 0.f ? x2 : SLOPEC * x2; x2 = a.z > 0 ? x2 : NEG_INFC;
        float x3 = ss + d.w; x3 = x3 > 0.f ? x3 : SLOPEC * x3; x3 = a.w > 0 ? x3 : NEG_INFC;
        v[c * 4 + 0] = x0; v[c * 4 + 1] = x1; v[c * 4 + 2] = x2; v[c * 4 + 3] = x3;
        vmax = fmaxf(vmax, fmaxf(fmaxf(x0, x1), fmaxf(x2, x3)));
    }
#pragma unroll
    for (int off = 32; off; off >>= 1) vmax = fmaxf(vmax, __shfl_xor(vmax, off));
    if ((tid & 63) == 0) wred[tid >> 6] = vmax;
    __syncthreads();
    vmax = fmaxf(fmaxf(wred[0], wred[1]), fmaxf(wred[2], wred[3]));

    float sum = 0.f;
#pragma unroll
    for (int c = 0; c < 16; c++) {
        v[c] = __expf(v[c] - vmax);
        sum += v[c];
    }
#pragma unroll
    for (int off = 32; off; off >>= 1) sum += __shfl_xor(sum, off);
    if ((tid & 63) == 0) wred2[tid >> 6] = sum;
    __syncthreads();
    sum = wred2[0] + wred2[1] + wred2[2] + wred2[3];
    const float inv = 1.0f / sum;

    float4* o4 = (float4*)(attn + (long)row * NN);
    short4v* b4 = (short4v*)(attnB + (long)row * NN);
#pragma unroll
    for (int c = 0; c < 4; c++) {
        int idx = c * 256 + tid;
        float4 o;
        o.x = v[c * 4 + 0] * inv; o.y = v[c * 4 + 1] * inv;
        o.z = v[c * 4 + 2] * inv; o.w = v[c * 4 + 3] * inv;
        o4[idx] = o;
        short4v sb;
        sb.x = f2bf(o.x); sb.y = f2bf(o.y); sb.z = f2bf(o.z); sb.w = f2bf(o.w);
        b4[idx] = sb;
    }
}

// ---------------------------------------------------------------------------
// pool[c] += sum over 64 rows of sentence[m][c]   (grid 64, pool zero-init)
// ---------------------------------------------------------------------------
__global__ __launch_bounds__(256) void k_pool(const float* __restrict__ sent,
                                              float* __restrict__ pool) {
    const int tid = threadIdx.x;  // float4 col index 0..255
    const int r0 = blockIdx.x * 64;
    float4 acc = {0.f, 0.f, 0.f, 0.f};
    const float4* s4 = (const float4*)sent;
#pragma unroll 4
    for (int r = 0; r < 64; r++) {
        float4 v = s4[(long)(r0 + r) * 256 + tid];
        acc.x += v.x; acc.y += v.y; acc.z += v.z; acc.w += v.w;
    }
    atomicAdd(pool + tid * 4 + 0, acc.x);
    atomicAdd(pool + tid * 4 + 1, acc.y);
    atomicAdd(pool + tid * 4 + 2, acc.z);
    atomicAdd(pool + tid * 4 + 3, acc.w);
}

// ---------------------------------------------------------------------------
// pool mean + classifier + 2-way softmax
// ---------------------------------------------------------------------------
__global__ __launch_bounds__(256) void k_final(const float* __restrict__ pool_acc,
                                               const float* __restrict__ clf_w,
                                               const float* __restrict__ clf_b,
                                               float* __restrict__ out_pool,
                                               float* __restrict__ out_label) {
    __shared__ float r0[4], r1[4];
    const int tid = threadIdx.x;
    float l0 = 0.f, l1 = 0.f;
#pragma unroll
    for (int q = 0; q < 4; q++) {
        int f = q * 256 + tid;
        float p = pool_acc[f] * (1.0f / NN);
        out_pool[f] = p;
        l0 += p * clf_w[f * 2 + 0];
        l1 += p * clf_w[f * 2 + 1];
    }
#pragma unroll
    for (int off = 32; off; off >>= 1) {
        l0 += __shfl_xor(l0, off);
        l1 += __shfl_xor(l1, off);
    }
    if ((tid & 63) == 0) { r0[tid >> 6] = l0; r1[tid >> 6] = l1; }
    __syncthreads();
    if (tid == 0) {
        float L0 = r0[0] + r0[1] + r0[2] + r0[3] + clf_b[0];
        float L1 = r1[0] + r1[1] + r1[2] + r1[3] + clf_b[1];
        float m = fmaxf(L0, L1);
        float e0 = __expf(L0 - m), e1 = __expf(L1 - m);
        float s = e0 + e1;
        out_label[0] = e0 / s;
        out_label[1] = e1 / s;
    }
}

// ---------------------------------------------------------------------------
extern "C" void kernel_launch(void* const* d_in, const int* in_sizes, int n_in,
                              void* d_out, int out_size, void* d_ws,
                              size_t ws_size, hipStream_t stream) {
    const int* inSen = (const int*)d_in[0];
    const int* adj = (const int*)d_in[1];
    const float* emb = (const float*)d_in[2];
    const float* W = (const float*)d_in[3];
    const float* a_src = (const float*)d_in[4];
    const float* a_dst = (const float*)d_in[5];
    const float* clf_w = (const float*)d_in[6];
    const float* clf_b = (const float*)d_in[7];

    float* out = (float*)d_out;
    float* out_pool = out;
    float* attn = out + 1024;
    float* sentence = out + 1024 + (long)NN * NN;
    float* out_label = out + 1024 + (long)NN * NN + (long)NN * WF;

    // ws layout (bytes):
    //   X     [NN][ED] bf16          8 MB   @ 0
    //   Wt    [WF][ED] bf16          2 MB   @ 8 MB
    //   Ht    [WF][NN] bf16          8 MB   @ 10 MB
    //   P1 / attnB (aliased)        32 MB   @ 18 MB
    //   s_src, s_dst, pool          small   @ 50 MB
    char* ws = (char*)d_ws;
    short* X = (short*)ws;
    short* Wt = (short*)(ws + (8l << 20));
    short* Ht = (short*)(ws + (10l << 20));
    float* P1 = (float*)(ws + (18l << 20));
    short* attnB = (short*)(ws + (18l << 20));
    float* s_src = (float*)(ws + (50l << 20));
    float* s_dst = s_src + NN;
    float* pool = s_dst + NN;

    hipMemsetAsync(s_src, 0, (2 * NN + WF) * sizeof(float), stream);
    hipMemsetAsync(sentence, 0, (long)NN * WF * sizeof(float), stream);

    k_wt<<<dim3(16, 16), 256, 0, stream>>>(W, Wt);
    k_gather<<<NN, 256, 0, stream>>>(inSen, emb, X);

    // GEMM1: Ht[f][i] = sum_k Wt[f][k] * X[i][k]   (M=WF, N=NN, K=ED, split 2)
    gemm_bt2<false><<<dim3(NN / 128, WF / 128, 2), 256, 0, stream>>>(
        Wt, X, WF, NN, ED, ED / 2, P1);
    k_reduce1<<<(WF * NN) / (256 * 8), 256, 0, stream>>>(P1, Ht);

    k_scores<<<dim3(NN / 256, WF / 256), 256, 0, stream>>>(Ht, a_src, a_dst,
                                                           s_src, s_dst);
    k_attn<<<NN, 256, 0, stream>>>(adj, s_src, s_dst, attn, attnB);

    // GEMM2: sentence[i][f] = sum_k attnB[i][k] * Ht[f][k] (M=NN,N=WF,K=NN, split 4)
    gemm_bt2<true><<<dim3(WF / 128, NN / 128, 4), 256, 0, stream>>>(
        attnB, Ht, NN, WF, NN, NN / 4, sentence);

    k_pool<<<NN / 64, 256, 0, stream>>>(sentence, pool);
    k_final<<<1, 256, 0, stream>>>(pool, clf_w, clf_b, out_pool, out_label);
}

// Round 3
// 446.453 us; speedup vs baseline: 1.3772x; 1.0538x over previous
//
#include <hip/hip_runtime.h>
#include <hip/hip_bf16.h>

#define NN 4096      // nodes
#define ED 1024      // edim
#define WF 1024      // wfeat
#define SLOPEC 0.01f
#define NEG_INFC -1e9f

typedef __attribute__((ext_vector_type(8))) short bf16x8;
typedef __attribute__((ext_vector_type(4))) short short4v;
typedef __attribute__((ext_vector_type(4))) float f32x4;

__device__ __forceinline__ float bf2f(short s) {
    union { unsigned u; float f; } v;
    v.u = ((unsigned)(unsigned short)s) << 16;
    return v.f;
}
__device__ __forceinline__ short f2bf(float f) {
    unsigned u = __float_as_uint(f);
    unsigned r = u + 0x7FFFu + ((u >> 16) & 1u);   // RNE (finite data)
    return (short)(r >> 16);
}

typedef __attribute__((address_space(3))) unsigned lds_u32;
typedef const __attribute__((address_space(1))) unsigned gbl_u32;
__device__ __forceinline__ void g2l16(const short* g, short* l) {
    __builtin_amdgcn_global_load_lds((gbl_u32*)g, (lds_u32*)l, 16, 0, 0);
}

// ---------------------------------------------------------------------------
// Transpose + convert W [ED][WF] fp32 -> Wt [WF][ED] bf16
// ---------------------------------------------------------------------------
__global__ __launch_bounds__(256) void k_wt(const float* __restrict__ W,
                                            short* __restrict__ Wt) {
    __shared__ float t[64][65];
    const int k0 = blockIdx.y * 64, n0 = blockIdx.x * 64;
    const int tx = threadIdx.x & 63, ty = threadIdx.x >> 6;
#pragma unroll
    for (int p = 0; p < 16; p++) {
        int r = p * 4 + ty;
        t[r][tx] = W[(long)(k0 + r) * WF + n0 + tx];
    }
    __syncthreads();
#pragma unroll
    for (int p = 0; p < 16; p++) {
        int r = p * 4 + ty;  // n index
        Wt[(long)(n0 + r) * ED + k0 + tx] = f2bf(t[tx][r]);
    }
}

// ---------------------------------------------------------------------------
// Gather + convert: X[i][k] = bf16(emb[inSen[i]][k]),  X: [NN][ED]
// ---------------------------------------------------------------------------
__global__ __launch_bounds__(256) void k_gather(const int* __restrict__ inSen,
                                                const float* __restrict__ emb,
                                                short* __restrict__ X) {
    const int row = blockIdx.x;
    const int tid = threadIdx.x;
    const long idx = inSen[row];
    const float4 v = ((const float4*)(emb + idx * ED))[tid];
    short4v s;
    s.x = f2bf(v.x); s.y = f2bf(v.y); s.z = f2bf(v.z); s.w = f2bf(v.w);
    *(short4v*)(X + (long)row * ED + tid * 4) = s;
}

// ---------------------------------------------------------------------------
// GEMM (m97 structure): C[M][N](+)= A[M][K] * Bt[N][K], bf16 in.
// Tile BM x BN, BK=32, 256 thr = 4 waves (2x2). global_load_lds width=16.
// BF16_OUT: repack via LDS, store bf16 C directly (no split-K, z ignored).
// else:     store fp32 partial at Cout + blockIdx.z*MN (split-K partials).
// ---------------------------------------------------------------------------
template <int BM, int BN, bool BF16_OUT>
__global__ __launch_bounds__(256, 2) void gemm_bt2(
    const short* __restrict__ A, const short* __restrict__ Bt,
    int M, int N, int K, int Kc, void* __restrict__ Cout, long MN) {
    constexpr int TM = BM / 32;           // m-frags per wave
    constexpr int TN = BN / 32;           // n-frags per wave
    constexpr int STAGE = BM * 32 + BN * 32;
    constexpr int SMEMSZ = (BF16_OUT && BM * BN > STAGE) ? BM * BN : STAGE;
    __shared__ __align__(16) short smem[SMEMSZ];
    short* sA = smem;
    short* sB = smem + BM * 32;

    const int tid = threadIdx.x;
    const int lane = tid & 63;
    const int wid = tid >> 6;
    const int wm = wid >> 1, wn = wid & 1;
    const int n0 = blockIdx.x * BN;
    const int m0 = blockIdx.y * BM;
    const int ks = blockIdx.z * Kc;

    const int srow = tid >> 2;        // 0..63
    const int sc8 = (tid & 3) * 8;    // 0,8,16,24
    const int l15 = lane & 15;
    const int lhi = lane >> 4;

    f32x4 acc[TM][TN];
#pragma unroll
    for (int t = 0; t < TM; t++)
#pragma unroll
        for (int u = 0; u < TN; u++) acc[t][u] = (f32x4){0.f, 0.f, 0.f, 0.f};

    const short* Ab = A + (long)(m0 + srow) * K + ks + sc8;
    const short* Bb = Bt + (long)(n0 + srow) * K + ks + sc8;
    const long rstep = (long)64 * K;   // 64 rows

    for (int k0 = 0; k0 < Kc; k0 += 32) {
#pragma unroll
        for (int p = 0; p < BM / 64; p++)
            g2l16(Ab + p * rstep + k0, sA + (p * 256 + wid * 64) * 8);
#pragma unroll
        for (int p = 0; p < BN / 64; p++)
            g2l16(Bb + p * rstep + k0, sB + (p * 256 + wid * 64) * 8);
        __syncthreads();   // drains vmcnt for global_load_lds

        bf16x8 af[TM], bfr[TN];
#pragma unroll
        for (int t = 0; t < TM; t++)
            af[t] = *(const bf16x8*)&sA[(wm * (BM / 2) + t * 16 + l15) * 32 + lhi * 8];
#pragma unroll
        for (int u = 0; u < TN; u++)
            bfr[u] = *(const bf16x8*)&sB[(wn * (BN / 2) + u * 16 + l15) * 32 + lhi * 8];
#pragma unroll
        for (int t = 0; t < TM; t++)
#pragma unroll
            for (int u = 0; u < TN; u++)
                acc[t][u] = __builtin_amdgcn_mfma_f32_16x16x32_bf16(
                    af[t], bfr[u], acc[t][u], 0, 0, 0);
        __syncthreads();
    }

    // Epilogue. D mapping per 16x16 tile: col = l15, row = lhi*4 + r
    if (BF16_OUT) {
        short* sT = smem;   // safe: last loop iteration ended with a barrier
#pragma unroll
        for (int t = 0; t < TM; t++)
#pragma unroll
            for (int u = 0; u < TN; u++)
#pragma unroll
                for (int r = 0; r < 4; r++) {
                    int m = wm * (BM / 2) + t * 16 + lhi * 4 + r;
                    int n = wn * (BN / 2) + u * 16 + l15;
                    sT[m * BN + n] = f2bf(acc[t][u][r]);
                }
        __syncthreads();
        short* C = (short*)Cout;
#pragma unroll
        for (int q = 0; q < BM * BN / 2048; q++) {
            int idx = q * 256 + tid;
            int row = idx / (BN / 8);
            int c8 = (idx % (BN / 8)) * 8;
            *(bf16x8*)(C + (long)(m0 + row) * N + n0 + c8) =
                *(const bf16x8*)&sT[row * BN + c8];
        }
    } else {
        float* P = (float*)Cout + (long)blockIdx.z * MN;
#pragma unroll
        for (int t = 0; t < TM; t++)
#pragma unroll
            for (int u = 0; u < TN; u++)
#pragma unroll
                for (int r = 0; r < 4; r++) {
                    int m = wm * (BM / 2) + t * 16 + lhi * 4 + r;
                    int n = wn * (BN / 2) + u * 16 + l15;
                    P[(long)(m0 + m) * N + n0 + n] = acc[t][u][r];
                }
    }
}

// ---------------------------------------------------------------------------
// scores: s_src[i] += sum_{f in chunk} Ht[f][i]*a_src[f]   (atomic over chunks)
// grid (NN/256, WF/256)
// ---------------------------------------------------------------------------
__global__ __launch_bounds__(256) void k_scores(const short* __restrict__ Ht,
                                                const float* __restrict__ a_src,
                                                const float* __restrict__ a_dst,
                                                float* __restrict__ s_src,
                                                float* __restrict__ s_dst) {
    const int i = blockIdx.x * 256 + threadIdx.x;
    const int f0 = blockIdx.y * 256;
    float as = 0.f, ad = 0.f;
#pragma unroll 8
    for (int f = f0; f < f0 + 256; f++) {
        float hv = bf2f(Ht[(long)f * NN + i]);
        as += hv * a_src[f];
        ad += hv * a_dst[f];
    }
    atomicAdd(s_src + i, as);
    atomicAdd(s_dst + i, ad);
}

// ---------------------------------------------------------------------------
// Masked softmax row -> attn fp32 (d_out) + attnB bf16 (ws, GEMM2 A operand)
// ---------------------------------------------------------------------------
__global__ __launch_bounds__(256) void k_attn(const int* __restrict__ adj,
                                              const float* __restrict__ s_src,
                                              const float* __restrict__ s_dst,
                                              float* __restrict__ attn,
                                              short* __restrict__ attnB) {
    __shared__ float wred[4];
    __shared__ float wred2[4];
    const int row = blockIdx.x;
    const int tid = threadIdx.x;
    const float ss = s_src[row];
    const int4* adj4 = (const int4*)(adj + (long)row * NN);
    const float4* sd4 = (const float4*)s_dst;
    float v[16];
    float vmax = -3e38f;
#pragma unroll
    for (int c = 0; c < 4; c++) {
        int idx = c * 256 + tid;
        int4 a = adj4[idx];
        float4 d = sd4[idx];
        float x0 = ss + d.x; x0 = x0 > 0.f ? x0 : SLOPEC * x0; x0 = a.x > 0 ? x0 : NEG_INFC;
        float x1 = ss + d.y; x1 = x1 > 0.f ? x1 : SLOPEC * x1; x1 = a.y > 0 ? x1 : NEG_INFC;
        float x2 = ss + d.z; x2 = x2 > 0.f ? x2 : SLOPEC * x2; x2 = a.z > 0 ? x2 : NEG_INFC;
        float x3 = ss + d.w; x3 = x3 > 0.f ? x3 : SLOPEC * x3; x3 = a.w > 0 ? x3 : NEG_INFC;
        v[c * 4 + 0] = x0; v[c * 4 + 1] = x1; v[c * 4 + 2] = x2; v[c * 4 + 3] = x3;
        vmax = fmaxf(vmax, fmaxf(fmaxf(x0, x1), fmaxf(x2, x3)));
    }
#pragma unroll
    for (int off = 32; off; off >>= 1) vmax = fmaxf(vmax, __shfl_xor(vmax, off));
    if ((tid & 63) == 0) wred[tid >> 6] = vmax;
    __syncthreads();
    vmax = fmaxf(fmaxf(wred[0], wred[1]), fmaxf(wred[2], wred[3]));

    float sum = 0.f;
#pragma unroll
    for (int c = 0; c < 16; c++) {
        v[c] = __expf(v[c] - vmax);
        sum += v[c];
    }
#pragma unroll
    for (int off = 32; off; off >>= 1) sum += __shfl_xor(sum, off);
    if ((tid & 63) == 0) wred2[tid >> 6] = sum;
    __syncthreads();
    sum = wred2[0] + wred2[1] + wred2[2] + wred2[3];
    const float inv = 1.0f / sum;

    float4* o4 = (float4*)(attn + (long)row * NN);
    short4v* b4 = (short4v*)(attnB + (long)row * NN);
#pragma unroll
    for (int c = 0; c < 4; c++) {
        int idx = c * 256 + tid;
        float4 o;
        o.x = v[c * 4 + 0] * inv; o.y = v[c * 4 + 1] * inv;
        o.z = v[c * 4 + 2] * inv; o.w = v[c * 4 + 3] * inv;
        o4[idx] = o;
        short4v sb;
        sb.x = f2bf(o.x); sb.y = f2bf(o.y); sb.z = f2bf(o.z); sb.w = f2bf(o.w);
        b4[idx] = sb;
    }
}

// ---------------------------------------------------------------------------
// reduce2: sentence[i][f] = P[0][i][f] + P[1][i][f]; pool[f] += colsum
// grid NN/16 = 256 blocks; block handles 16 rows x full WF (256 float4)
// ---------------------------------------------------------------------------
__global__ __launch_bounds__(256) void k_reduce2(const float* __restrict__ P,
                                                 float* __restrict__ sent,
                                                 float* __restrict__ pool) {
    const int tid = threadIdx.x;            // float4 column 0..255
    const long MN4 = (long)NN * WF / 4;
    const float4* P0 = (const float4*)P;
    const float4* P1 = P0 + MN4;
    float4* s4 = (float4*)sent;
    float4 acc = {0.f, 0.f, 0.f, 0.f};
#pragma unroll 4
    for (int r = 0; r < 16; r++) {
        long e = (long)(blockIdx.x * 16 + r) * 256 + tid;
        float4 a = P0[e], b = P1[e];
        float4 s;
        s.x = a.x + b.x; s.y = a.y + b.y; s.z = a.z + b.z; s.w = a.w + b.w;
        s4[e] = s;
        acc.x += s.x; acc.y += s.y; acc.z += s.z; acc.w += s.w;
    }
    atomicAdd(pool + tid * 4 + 0, acc.x);
    atomicAdd(pool + tid * 4 + 1, acc.y);
    atomicAdd(pool + tid * 4 + 2, acc.z);
    atomicAdd(pool + tid * 4 + 3, acc.w);
}

// ---------------------------------------------------------------------------
// pool mean + classifier + 2-way softmax
// ---------------------------------------------------------------------------
__global__ __launch_bounds__(256) void k_final(const float* __restrict__ pool_acc,
                                               const float* __restrict__ clf_w,
                                               const float* __restrict__ clf_b,
                                               float* __restrict__ out_pool,
                                               float* __restrict__ out_label) {
    __shared__ float r0[4], r1[4];
    const int tid = threadIdx.x;
    float l0 = 0.f, l1 = 0.f;
#pragma unroll
    for (int q = 0; q < 4; q++) {
        int f = q * 256 + tid;
        float p = pool_acc[f] * (1.0f / NN);
        out_pool[f] = p;
        l0 += p * clf_w[f * 2 + 0];
        l1 += p * clf_w[f * 2 + 1];
    }
#pragma unroll
    for (int off = 32; off; off >>= 1) {
        l0 += __shfl_xor(l0, off);
        l1 += __shfl_xor(l1, off);
    }
    if ((tid & 63) == 0) { r0[tid >> 6] = l0; r1[tid >> 6] = l1; }
    __syncthreads();
    if (tid == 0) {
        float L0 = r0[0] + r0[1] + r0[2] + r0[3] + clf_b[0];
        float L1 = r1[0] + r1[1] + r1[2] + r1[3] + clf_b[1];
        float m = fmaxf(L0, L1);
        float e0 = __expf(L0 - m), e1 = __expf(L1 - m);
        float s = e0 + e1;
        out_label[0] = e0 / s;
        out_label[1] = e1 / s;
    }
}

// ---------------------------------------------------------------------------
extern "C" void kernel_launch(void* const* d_in, const int* in_sizes, int n_in,
                              void* d_out, int out_size, void* d_ws,
                              size_t ws_size, hipStream_t stream) {
    const int* inSen = (const int*)d_in[0];
    const int* adj = (const int*)d_in[1];
    const float* emb = (const float*)d_in[2];
    const float* W = (const float*)d_in[3];
    const float* a_src = (const float*)d_in[4];
    const float* a_dst = (const float*)d_in[5];
    const float* clf_w = (const float*)d_in[6];
    const float* clf_b = (const float*)d_in[7];

    float* out = (float*)d_out;
    float* out_pool = out;
    float* attn = out + 1024;
    float* sentence = out + 1024 + (long)NN * NN;
    float* out_label = out + 1024 + (long)NN * NN + (long)NN * WF;

    // ws layout:
    //   X     [NN][ED]  bf16   8 MB  @ 0
    //   Wt    [WF][ED]  bf16   2 MB  @ 8 MB
    //   Ht    [WF][NN]  bf16   8 MB  @ 10 MB
    //   attnB [NN][NN]  bf16  33.6MB @ 18 MB
    //   P2    [2][NN][WF] f32 33.6MB @ 52 MB
    //   s_src/s_dst/pool       small @ 86 MB
    char* ws = (char*)d_ws;
    short* X = (short*)ws;
    short* Wt = (short*)(ws + (8l << 20));
    short* Ht = (short*)(ws + (10l << 20));
    short* attnB = (short*)(ws + (18l << 20));
    float* P2 = (float*)(ws + (52l << 20));
    float* s_src = (float*)(ws + (86l << 20));
    float* s_dst = s_src + NN;
    float* pool = s_dst + NN;

    hipMemsetAsync(s_src, 0, (2 * NN + WF) * sizeof(float), stream);

    k_wt<<<dim3(16, 16), 256, 0, stream>>>(W, Wt);
    k_gather<<<NN, 256, 0, stream>>>(inSen, emb, X);

    // GEMM1: Ht[f][i] = sum_k Wt[f][k] * X[i][k]
    // M=WF, N=NN, K=ED; BM=64, BN=128 -> 512 blocks, bf16 direct out
    gemm_bt2<64, 128, true><<<dim3(NN / 128, WF / 64, 1), 256, 0, stream>>>(
        Wt, X, WF, NN, ED, ED, Ht, 0);

    k_scores<<<dim3(NN / 256, WF / 256), 256, 0, stream>>>(Ht, a_src, a_dst,
                                                           s_src, s_dst);
    k_attn<<<NN, 256, 0, stream>>>(adj, s_src, s_dst, attn, attnB);

    // GEMM2: sentence[i][f] = sum_k attnB[i][k] * Ht[f][k]
    // M=NN, N=WF, K=NN; split-K=2, fp32 partial stores
    gemm_bt2<128, 128, false><<<dim3(WF / 128, NN / 128, 2), 256, 0, stream>>>(
        attnB, Ht, NN, WF, NN, NN / 2, P2, (long)NN * WF);

    k_reduce2<<<NN / 16, 256, 0, stream>>>(P2, sentence, pool);
    k_final<<<1, 256, 0, stream>>>(pool, clf_w, clf_b, out_pool, out_label);
}

// Round 5
// 431.876 us; speedup vs baseline: 1.4236x; 1.0338x over previous
//
#include <hip/hip_runtime.h>
#include <hip/hip_bf16.h>

#define NN 4096      // nodes
#define ED 1024      // edim
#define WF 1024      // wfeat
#define SLOPEC 0.01f
#define NEG_INFC -1e9f

typedef __attribute__((ext_vector_type(8))) short bf16x8;
typedef __attribute__((ext_vector_type(4))) short short4v;
typedef __attribute__((ext_vector_type(4))) float f32x4;
typedef __attribute__((ext_vector_type(4))) int int4v;

__device__ __forceinline__ float bf2f(short s) {
    union { unsigned u; float f; } v;
    v.u = ((unsigned)(unsigned short)s) << 16;
    return v.f;
}
__device__ __forceinline__ short f2bf(float f) {
    unsigned u = __float_as_uint(f);
    unsigned r = u + 0x7FFFu + ((u >> 16) & 1u);   // RNE (finite data)
    return (short)(r >> 16);
}

typedef __attribute__((address_space(3))) unsigned lds_u32;
typedef const __attribute__((address_space(1))) unsigned gbl_u32;
__device__ __forceinline__ void g2l16(const short* g, short* l) {
    __builtin_amdgcn_global_load_lds((gbl_u32*)g, (lds_u32*)l, 16, 0, 0);
}

// ---------------------------------------------------------------------------
// Fused prep:
//  blocks [0,256): transpose+convert W [ED][WF] fp32 -> Wt [WF][ED] bf16
//  blocks [256,256+NN): gather+convert X[i][k] = bf16(emb[inSen[i]][k])
// ---------------------------------------------------------------------------
__global__ __launch_bounds__(256) void k_prep(const float* __restrict__ W,
                                              short* __restrict__ Wt,
                                              const int* __restrict__ inSen,
                                              const float* __restrict__ emb,
                                              short* __restrict__ X) {
    if (blockIdx.x < 256) {
        __shared__ float t[64][65];
        const int n0 = (blockIdx.x & 15) * 64, k0 = (blockIdx.x >> 4) * 64;
        const int tx = threadIdx.x & 63, ty = threadIdx.x >> 6;
#pragma unroll
        for (int p = 0; p < 16; p++) {
            int r = p * 4 + ty;
            t[r][tx] = W[(long)(k0 + r) * WF + n0 + tx];
        }
        __syncthreads();
#pragma unroll
        for (int p = 0; p < 16; p++) {
            int r = p * 4 + ty;  // n index
            Wt[(long)(n0 + r) * ED + k0 + tx] = f2bf(t[tx][r]);
        }
    } else {
        const int row = blockIdx.x - 256;
        const int tid = threadIdx.x;
        const long idx = inSen[row];
        const float4 v = ((const float4*)(emb + idx * ED))[tid];
        short4v s;
        s.x = f2bf(v.x); s.y = f2bf(v.y); s.z = f2bf(v.z); s.w = f2bf(v.w);
        *(short4v*)(X + (long)row * ED + tid * 4) = s;
    }
}

// ---------------------------------------------------------------------------
// GEMM (m97 structure): C[M][N](+)= A[M][K] * Bt[N][K], bf16 in.
// Tile BM x BN, BK=32, 256 thr = 4 waves (2x2). global_load_lds width=16.
// BF16_OUT: repack via LDS, store bf16 C directly (no split-K).
//   + DO_SCORES: also atomically accumulate s_src/s_dst (column scores).
// else:     store fp32 partial at Cout + blockIdx.z*MN (split-K partials).
// ---------------------------------------------------------------------------
template <int BM, int BN, bool BF16_OUT, bool DO_SCORES>
__global__ __launch_bounds__(256, 2) void gemm_bt2(
    const short* __restrict__ A, const short* __restrict__ Bt,
    int M, int N, int K, int Kc, void* __restrict__ Cout, long MN,
    const float* __restrict__ a_src, const float* __restrict__ a_dst,
    float* __restrict__ s_src, float* __restrict__ s_dst) {
    constexpr int TM = BM / 32;           // m-frags per wave
    constexpr int TN = BN / 32;           // n-frags per wave
    constexpr int STAGE = BM * 32 + BN * 32;
    constexpr int SMEMSZ = (BF16_OUT && BM * BN > STAGE) ? BM * BN : STAGE;
    __shared__ __align__(16) short smem[SMEMSZ];
    short* sA = smem;
    short* sB = smem + BM * 32;

    const int tid = threadIdx.x;
    const int lane = tid & 63;
    const int wid = tid >> 6;
    const int wm = wid >> 1, wn = wid & 1;
    const int n0 = blockIdx.x * BN;
    const int m0 = blockIdx.y * BM;
    const int ks = blockIdx.z * Kc;

    const int srow = tid >> 2;        // 0..63
    const int sc8 = (tid & 3) * 8;    // 0,8,16,24
    const int l15 = lane & 15;
    const int lhi = lane >> 4;

    f32x4 acc[TM][TN];
#pragma unroll
    for (int t = 0; t < TM; t++)
#pragma unroll
        for (int u = 0; u < TN; u++) acc[t][u] = (f32x4){0.f, 0.f, 0.f, 0.f};

    const short* Ab = A + (long)(m0 + srow) * K + ks + sc8;
    const short* Bb = Bt + (long)(n0 + srow) * K + ks + sc8;
    const long rstep = (long)64 * K;   // 64 rows

    for (int k0 = 0; k0 < Kc; k0 += 32) {
#pragma unroll
        for (int p = 0; p < BM / 64; p++)
            g2l16(Ab + p * rstep + k0, sA + (p * 256 + wid * 64) * 8);
#pragma unroll
        for (int p = 0; p < BN / 64; p++)
            g2l16(Bb + p * rstep + k0, sB + (p * 256 + wid * 64) * 8);
        __syncthreads();   // drains vmcnt for global_load_lds

        bf16x8 af[TM], bfr[TN];
#pragma unroll
        for (int t = 0; t < TM; t++)
            af[t] = *(const bf16x8*)&sA[(wm * (BM / 2) + t * 16 + l15) * 32 + lhi * 8];
#pragma unroll
        for (int u = 0; u < TN; u++)
            bfr[u] = *(const bf16x8*)&sB[(wn * (BN / 2) + u * 16 + l15) * 32 + lhi * 8];
#pragma unroll
        for (int t = 0; t < TM; t++)
#pragma unroll
            for (int u = 0; u < TN; u++)
                acc[t][u] = __builtin_amdgcn_mfma_f32_16x16x32_bf16(
                    af[t], bfr[u], acc[t][u], 0, 0, 0);
        __syncthreads();
    }

    // Epilogue. D mapping per 16x16 tile: col = l15, row = lhi*4 + r
    if (BF16_OUT) {
        short* sT = smem;   // safe: last loop iteration ended with a barrier
#pragma unroll
        for (int t = 0; t < TM; t++)
#pragma unroll
            for (int u = 0; u < TN; u++)
#pragma unroll
                for (int r = 0; r < 4; r++) {
                    int m = wm * (BM / 2) + t * 16 + lhi * 4 + r;
                    int n = wn * (BN / 2) + u * 16 + l15;
                    sT[m * BN + n] = f2bf(acc[t][u][r]);
                }
        __syncthreads();
        short* C = (short*)Cout;
#pragma unroll
        for (int q = 0; q < BM * BN / 2048; q++) {
            int idx = q * 256 + tid;
            int row = idx / (BN / 8);
            int c8 = (idx % (BN / 8)) * 8;
            *(bf16x8*)(C + (long)(m0 + row) * N + n0 + c8) =
                *(const bf16x8*)&sT[row * BN + c8];
        }
        if (DO_SCORES) {
            // s_src[n] += sum_m Ht[m][n]*a_src[m] over this block's m-range
            float ps[TN], pd[TN];
#pragma unroll
            for (int u = 0; u < TN; u++) { ps[u] = 0.f; pd[u] = 0.f; }
#pragma unroll
            for (int t = 0; t < TM; t++)
#pragma unroll
                for (int r = 0; r < 4; r++) {
                    int m = m0 + wm * (BM / 2) + t * 16 + lhi * 4 + r;
                    float as = a_src[m], ad = a_dst[m];
#pragma unroll
                    for (int u = 0; u < TN; u++) {
                        ps[u] += acc[t][u][r] * as;
                        pd[u] += acc[t][u][r] * ad;
                    }
                }
#pragma unroll
            for (int u = 0; u < TN; u++) {
                ps[u] += __shfl_xor(ps[u], 16); ps[u] += __shfl_xor(ps[u], 32);
                pd[u] += __shfl_xor(pd[u], 16); pd[u] += __shfl_xor(pd[u], 32);
            }
            if (lane < 16) {
#pragma unroll
                for (int u = 0; u < TN; u++) {
                    int n = n0 + wn * (BN / 2) + u * 16 + lane;
                    atomicAdd(s_src + n, ps[u]);
                    atomicAdd(s_dst + n, pd[u]);
                }
            }
        }
    } else {
        float* P = (float*)Cout + (long)blockIdx.z * MN;
#pragma unroll
        for (int t = 0; t < TM; t++)
#pragma unroll
            for (int u = 0; u < TN; u++)
#pragma unroll
                for (int r = 0; r < 4; r++) {
                    int m = wm * (BM / 2) + t * 16 + lhi * 4 + r;
                    int n = wn * (BN / 2) + u * 16 + l15;
                    P[(long)(m0 + m) * N + n0 + n] = acc[t][u][r];
                }
    }
}

// ---------------------------------------------------------------------------
// Masked softmax row -> attn fp32 (d_out, NT) + attnB bf16 (ws, GEMM2 A)
// ---------------------------------------------------------------------------
__global__ __launch_bounds__(256) void k_attn(const int* __restrict__ adj,
                                              const float* __restrict__ s_src,
                                              const float* __restrict__ s_dst,
                                              float* __restrict__ attn,
                                              short* __restrict__ attnB) {
    __shared__ float wred[4];
    __shared__ float wred2[4];
    const int row = blockIdx.x;
    const int tid = threadIdx.x;
    const float ss = s_src[row];
    const int4v* adj4 = (const int4v*)(adj + (long)row * NN);
    const f32x4* sd4 = (const f32x4*)s_dst;
    float v[16];
    float vmax = -3e38f;
#pragma unroll
    for (int c = 0; c < 4; c++) {
        int idx = c * 256 + tid;
        int4v a = __builtin_nontemporal_load(&adj4[idx]);
        f32x4 d = sd4[idx];
        float x0 = ss + d.x; x0 = x0 > 0.f ? x0 : SLOPEC * x0; x0 = a.x > 0 ? x0 : NEG_INFC;
        float x1 = ss + d.y; x1 = x1 > 0.f ? x1 : SLOPEC * x1; x1 = a.y > 0 ? x1 : NEG_INFC;
        float x2 = ss + d.z; x2 = x2 > 0.f ? x2 : SLOPEC * x2; x2 = a.z > 0 ? x2 : NEG_INFC;
        float x3 = ss + d.w; x3 = x3 > 0.f ? x3 : SLOPEC * x3; x3 = a.w > 0 ? x3 : NEG_INFC;
        v[c * 4 + 0] = x0; v[c * 4 + 1] = x1; v[c * 4 + 2] = x2; v[c * 4 + 3] = x3;
        vmax = fmaxf(vmax, fmaxf(fmaxf(x0, x1), fmaxf(x2, x3)));
    }
#pragma unroll
    for (int off = 32; off; off >>= 1) vmax = fmaxf(vmax, __shfl_xor(vmax, off));
    if ((tid & 63) == 0) wred[tid >> 6] = vmax;
    __syncthreads();
    vmax = fmaxf(fmaxf(wred[0], wred[1]), fmaxf(wred[2], wred[3]));

    float sum = 0.f;
#pragma unroll
    for (int c = 0; c < 16; c++) {
        v[c] = __expf(v[c] - vmax);
        sum += v[c];
    }
#pragma unroll
    for (int off = 32; off; off >>= 1) sum += __shfl_xor(sum, off);
    if ((tid & 63) == 0) wred2[tid >> 6] = sum;
    __syncthreads();
    sum = wred2[0] + wred2[1] + wred2[2] + wred2[3];
    const float inv = 1.0f / sum;

    f32x4* o4 = (f32x4*)(attn + (long)row * NN);
    short4v* b4 = (short4v*)(attnB + (long)row * NN);
#pragma unroll
    for (int c = 0; c < 4; c++) {
        int idx = c * 256 + tid;
        f32x4 o;
        o.x = v[c * 4 + 0] * inv; o.y = v[c * 4 + 1] * inv;
        o.z = v[c * 4 + 2] * inv; o.w = v[c * 4 + 3] * inv;
        __builtin_nontemporal_store(o, &o4[idx]);
        short4v sb;
        sb.x = f2bf(o.x); sb.y = f2bf(o.y); sb.z = f2bf(o.z); sb.w = f2bf(o.w);
        b4[idx] = sb;
    }
}

// ---------------------------------------------------------------------------
// reduce2: sentence = sum of 4 split-K partials (NT store); pool += colsum
// grid NN/16 = 256 blocks; block handles 16 rows x full WF (256 float4)
// ---------------------------------------------------------------------------
__global__ __launch_bounds__(256) void k_reduce2(const float* __restrict__ P,
                                                 float* __restrict__ sent,
                                                 float* __restrict__ pool) {
    const int tid = threadIdx.x;            // float4 column 0..255
    const long MN4 = (long)NN * WF / 4;
    const f32x4* P0 = (const f32x4*)P;
    f32x4* s4 = (f32x4*)sent;
    f32x4 acc = {0.f, 0.f, 0.f, 0.f};
#pragma unroll 4
    for (int r = 0; r < 16; r++) {
        long e = (long)(blockIdx.x * 16 + r) * 256 + tid;
        f32x4 a = P0[e], b = P0[e + MN4];
        f32x4 c = P0[e + 2 * MN4], d = P0[e + 3 * MN4];
        f32x4 s = a + b + c + d;
        __builtin_nontemporal_store(s, &s4[e]);
        acc += s;
    }
    atomicAdd(pool + tid * 4 + 0, acc.x);
    atomicAdd(pool + tid * 4 + 1, acc.y);
    atomicAdd(pool + tid * 4 + 2, acc.z);
    atomicAdd(pool + tid * 4 + 3, acc.w);
}

// ---------------------------------------------------------------------------
// pool mean + classifier + 2-way softmax
// ---------------------------------------------------------------------------
__global__ __launch_bounds__(256) void k_final(const float* __restrict__ pool_acc,
                                               const float* __restrict__ clf_w,
                                               const float* __restrict__ clf_b,
                                               float* __restrict__ out_pool,
                                               float* __restrict__ out_label) {
    __shared__ float r0[4], r1[4];
    const int tid = threadIdx.x;
    float l0 = 0.f, l1 = 0.f;
#pragma unroll
    for (int q = 0; q < 4; q++) {
        int f = q * 256 + tid;
        float p = pool_acc[f] * (1.0f / NN);
        out_pool[f] = p;
        l0 += p * clf_w[f * 2 + 0];
        l1 += p * clf_w[f * 2 + 1];
    }
#pragma unroll
    for (int off = 32; off; off >>= 1) {
        l0 += __shfl_xor(l0, off);
        l1 += __shfl_xor(l1, off);
    }
    if ((tid & 63) == 0) { r0[tid >> 6] = l0; r1[tid >> 6] = l1; }
    __syncthreads();
    if (tid == 0) {
        float L0 = r0[0] + r0[1] + r0[2] + r0[3] + clf_b[0];
        float L1 = r1[0] + r1[1] + r1[2] + r1[3] + clf_b[1];
        float m = fmaxf(L0, L1);
        float e0 = __expf(L0 - m), e1 = __expf(L1 - m);
        float s = e0 + e1;
        out_label[0] = e0 / s;
        out_label[1] = e1 / s;
    }
}

// ---------------------------------------------------------------------------
extern "C" void kernel_launch(void* const* d_in, const int* in_sizes, int n_in,
                              void* d_out, int out_size, void* d_ws,
                              size_t ws_size, hipStream_t stream) {
    const int* inSen = (const int*)d_in[0];
    const int* adj = (const int*)d_in[1];
    const float* emb = (const float*)d_in[2];
    const float* W = (const float*)d_in[3];
    const float* a_src = (const float*)d_in[4];
    const float* a_dst = (const float*)d_in[5];
    const float* clf_w = (const float*)d_in[6];
    const float* clf_b = (const float*)d_in[7];

    float* out = (float*)d_out;
    float* out_pool = out;
    float* attn = out + 1024;
    float* sentence = out + 1024 + (long)NN * NN;
    float* out_label = out + 1024 + (long)NN * NN + (long)NN * WF;

    // ws layout:
    //   X     [NN][ED]    bf16   8 MB  @ 0
    //   Wt    [WF][ED]    bf16   2 MB  @ 8 MB
    //   Ht    [WF][NN]    bf16   8 MB  @ 10 MB
    //   attnB [NN][NN]    bf16  33.6MB @ 18 MB
    //   P2    [4][NN][WF] f32   67.1MB @ 52 MB
    //   s_src/s_dst/pool         small @ 120 MB
    char* ws = (char*)d_ws;
    short* X = (short*)ws;
    short* Wt = (short*)(ws + (8l << 20));
    short* Ht = (short*)(ws + (10l << 20));
    short* attnB = (short*)(ws + (18l << 20));
    float* P2 = (float*)(ws + (52l << 20));
    float* s_src = (float*)(ws + (120l << 20));
    float* s_dst = s_src + NN;
    float* pool = s_dst + NN;

    (void)hipMemsetAsync(s_src, 0, (2 * NN + WF) * sizeof(float), stream);

    k_prep<<<256 + NN, 256, 0, stream>>>(W, Wt, inSen, emb, X);

    // GEMM1: Ht[f][i] = sum_k Wt[f][k] * X[i][k]
    // M=WF, N=NN, K=ED; BM=64, BN=128 -> 512 blocks, bf16 out + fused scores
    gemm_bt2<64, 128, true, true><<<dim3(NN / 128, WF / 64, 1), 256, 0, stream>>>(
        Wt, X, WF, NN, ED, ED, Ht, 0, a_src, a_dst, s_src, s_dst);

    k_attn<<<NN, 256, 0, stream>>>(adj, s_src, s_dst, attn, attnB);

    // GEMM2: sentence[i][f] = sum_k attnB[i][k] * Ht[f][k]
    // M=NN, N=WF, K=NN; split-K=4 -> 1024 blocks, fp32 partial stores
    gemm_bt2<128, 128, false, false><<<dim3(WF / 128, NN / 128, 4), 256, 0, stream>>>(
        attnB, Ht, NN, WF, NN, NN / 4, P2, (long)NN * WF,
        nullptr, nullptr, nullptr, nullptr);

    k_reduce2<<<NN / 16, 256, 0, stream>>>(P2, sentence, pool);
    k_final<<<1, 256, 0, stream>>>(pool, clf_w, clf_b, out_pool, out_label);
}